// Round 5
// baseline (323.325 us; speedup 1.0000x reference)
//
#include <hip/hip_runtime.h>
#include <math.h>

// Problem constants
#define BN 32768
#define DN 512
#define SN 32
#define LN 8
#define KN 256
#define N2 65536   // 2*BN
#define SPLIT 8    // blocks per group in k1/k3

typedef __attribute__((ext_vector_type(8))) short bf16x8;
typedef __attribute__((ext_vector_type(4))) float f32x4;
typedef __attribute__((ext_vector_type(8))) unsigned short ushort8v;

// workspace layout (byte offsets)
#define OFF_XBF     0ull            // ushort[N2*DN]            67108864
#define OFF_PART    67108864ull     // float[SPLIT*KN*DN]        4194304
#define OFF_CENTB   71303168ull     // ushort[KN*DN]              262144
#define OFF_PERM    71827456ull     // int[BN]                    131072
#define OFF_BASE    71958528ull     // int[KN+1]                    1028
#define OFF_OFFW    71959556ull     // int[KN]  (zero-based cursor) 1024
#define OFF_COUNTS  71960580ull     // int[KN]                      1024
#define OFF_SUMQ    71961604ull     // float[KN]                    1024
#define OFF_INVD    71962628ull     // float[KN]                    1024
#define OFF_LOSS    71963652ull     // float[1]                        4
#define OFF_BARS    71963656ull     // uint[6]: k0 {cnt,flag}, k3 done, k5 done
#define ZERO_OFF    OFF_OFFW
#define ZERO_BYTES  (71963680ull - OFF_OFFW)   // 4124

__device__ __forceinline__ float atomAddF(float* p, float v) {
  return unsafeAtomicAdd(p, v);   // hw global_atomic_add_f32 (coherence point)
}

// Relaxed grid barrier (k0 only: 32 blocks). All values crossing it are
// device-scope atomics read back with agent-scope loads -> no fences needed.
__device__ __forceinline__ void gridbar_relaxed(unsigned* cnt, unsigned* flag,
                                                unsigned nblocks) {
  asm volatile("s_waitcnt vmcnt(0)" ::: "memory");
  __syncthreads();
  if (threadIdx.x == 0) {
    unsigned a = __hip_atomic_fetch_add(cnt, 1u, __ATOMIC_RELAXED,
                                        __HIP_MEMORY_SCOPE_AGENT);
    if (a + 1u == nblocks) {
      __hip_atomic_store(flag, 1u, __ATOMIC_RELAXED, __HIP_MEMORY_SCOPE_AGENT);
    } else {
      while (!__hip_atomic_load(flag, __ATOMIC_RELAXED, __HIP_MEMORY_SCOPE_AGENT))
        __builtin_amdgcn_s_sleep(16);
    }
  }
  __syncthreads();
}

__device__ __forceinline__ ushort f2bf(float x) {
  union { float f; unsigned u; } v; v.f = x;
  unsigned u = v.u;
  unsigned r = (u + 0x7fffu + ((u >> 16) & 1u)) >> 16;  // RNE
  return (ushort)r;
}

__device__ __forceinline__ float bf2f(ushort x) {
  union { unsigned u; float f; } v; v.u = ((unsigned)x) << 16;
  return v.f;
}

// async 16B/lane global->LDS DMA (lands at lds base + lane*16)
__device__ __forceinline__ void async16(const void* g, void* l) {
  __builtin_amdgcn_global_load_lds(
      (const __attribute__((address_space(1))) unsigned int*)g,
      (__attribute__((address_space(3))) unsigned int*)l, 16, 0, 0);
}

// ---- k0: fused gid/hist + scan + scatter (32 blocks, relaxed grid-barrier) ----
// R3/R4-verified.
__global__ __launch_bounds__(256) void k0_all(const int* __restrict__ subject,
    const int* __restrict__ labels, int* __restrict__ counts, int* __restrict__ base,
    int* __restrict__ offw, int* __restrict__ perm, unsigned* __restrict__ bars) {
  __shared__ int lhist[KN];
  __shared__ int sh[KN];
  __shared__ int lbase[KN];
  const int t = threadIdx.x;
  const int b0 = blockIdx.x * 1024;
  lhist[t] = 0;
  __syncthreads();
  int g[4], lr[4];
#pragma unroll
  for (int k = 0; k < 4; ++k) {
    const int b = b0 + k * 256 + t;
    g[k] = subject[b] * LN + labels[b];
    lr[k] = atomicAdd(&lhist[g[k]], 1);
  }
  __syncthreads();
  const int h = lhist[t];
  if (h) atomicAdd(&counts[t], 2 * h);
  gridbar_relaxed(&bars[0], &bars[1], 32);
  const int rows = ((int)__hip_atomic_load((unsigned*)&counts[t], __ATOMIC_RELAXED,
                                           __HIP_MEMORY_SCOPE_AGENT)) >> 1;
  sh[t] = rows;
  __syncthreads();
  for (int d = 1; d < 256; d <<= 1) {
    int add = (t >= d) ? sh[t - d] : 0;
    __syncthreads();
    sh[t] += add;
    __syncthreads();
  }
  const int excl = sh[t] - rows;
  if (blockIdx.x == 0) {
    base[t] = excl;
    if (t == 255) base[256] = sh[255];
  }
  if (h) lbase[t] = excl + atomicAdd(&offw[t], h);
  __syncthreads();
#pragma unroll
  for (int k = 0; k < 4; ++k)
    perm[lbase[g[k]] + lr[k]] = b0 + k * 256 + t;
}

// ---- k1: sorted segment-reduce group sums + f32->bf16 conversion ----
// Each wave owns an independent row stream. Lane owns dims [lane*8, lane*8+8)
// -> 16B ushort8 stores to Xb (was 4x 8B). Partial layout/order bit-identical.
__global__ __launch_bounds__(256) void k1_sums(const float* __restrict__ X,
    const int* __restrict__ perm, const int* __restrict__ base,
    ushort* __restrict__ Xb, float* __restrict__ partial) {
  __shared__ float buf[4 * 512];
  const int g = blockIdx.x >> 3;
  const int s = blockIdx.x & (SPLIT - 1);
  const int t = threadIdx.x;
  const int w = t >> 6;
  const int lane = t & 63;
  const int start = base[g], end = base[g + 1];
  const int vs = s * 4 + w;              // stream 0..31

  float4 a0 = {0.f, 0.f, 0.f, 0.f};
  float4 a1 = {0.f, 0.f, 0.f, 0.f};

  int i = start + vs;
  if (i < end) {
    int idx = perm[i];
    const float* bp = X + (size_t)idx * 1024 + lane * 8;
    float4 x0  = *(const float4*)(bp);        // view0 dims lane*8..+3
    float4 x0b = *(const float4*)(bp + 4);    // view0 dims lane*8+4..+7
    float4 x1  = *(const float4*)(bp + 512);  // view1 dims lane*8..+3
    float4 x1b = *(const float4*)(bp + 516);  // view1 dims lane*8+4..+7
    while (true) {
      const int inext = i + 32;
      int idxn = idx;
      float4 y0 = x0, y0b = x0b, y1 = x1, y1b = x1b;
      if (inext < end) {
        idxn = perm[inext];
        const float* bn = X + (size_t)idxn * 1024 + lane * 8;
        y0  = *(const float4*)(bn);
        y0b = *(const float4*)(bn + 4);
        y1  = *(const float4*)(bn + 512);
        y1b = *(const float4*)(bn + 516);
      }
      a0.x += x0.x + x1.x;  a0.y += x0.y + x1.y;
      a0.z += x0.z + x1.z;  a0.w += x0.w + x1.w;
      a1.x += x0b.x + x1b.x; a1.y += x0b.y + x1b.y;
      a1.z += x0b.z + x1b.z; a1.w += x0b.w + x1b.w;
      ushort8v u0, u1;
      u0[0] = f2bf(x0.x);  u0[1] = f2bf(x0.y);  u0[2] = f2bf(x0.z);  u0[3] = f2bf(x0.w);
      u0[4] = f2bf(x0b.x); u0[5] = f2bf(x0b.y); u0[6] = f2bf(x0b.z); u0[7] = f2bf(x0b.w);
      u1[0] = f2bf(x1.x);  u1[1] = f2bf(x1.y);  u1[2] = f2bf(x1.z);  u1[3] = f2bf(x1.w);
      u1[4] = f2bf(x1b.x); u1[5] = f2bf(x1b.y); u1[6] = f2bf(x1b.z); u1[7] = f2bf(x1b.w);
      *(ushort8v*)(Xb + (size_t)idx * DN + lane * 8) = u0;
      *(ushort8v*)(Xb + (size_t)(idx + BN) * DN + lane * 8) = u1;
      if (inext >= end) break;
      i = inext; idx = idxn; x0 = y0; x0b = y0b; x1 = y1; x1b = y1b;
    }
  }
  *(float4*)&buf[w * 512 + lane * 8] = a0;
  *(float4*)&buf[w * 512 + lane * 8 + 4] = a1;
  __syncthreads();
  if (t < 128) {
    float4 r = {0.f, 0.f, 0.f, 0.f};
#pragma unroll
    for (int ww = 0; ww < 4; ++ww) {
      float4 v = *(float4*)&buf[ww * 512 + t * 4];
      r.x += v.x; r.y += v.y; r.z += v.z; r.w += v.w;
    }
    *(float4*)&partial[((size_t)s * KN + g) * DN + t * 4] = r;
  }
}

// ---- k3: per-block centroid rebuild (replaces k1b) + dist^(1/4) accumulation
//          + fused k4 density via last-block-out election ----
// Each block sums the 8 split-partials of ITS OWN group g (16KB L2-hit read,
// redundant x8) -> f32 centroid; s==0 blocks persist bf16 centB for k5.
// Bit-identical to old k1b math (same split order, f2bf(sum/count)).
__global__ __launch_bounds__(256) void k3_dist(const ushort* __restrict__ Xb,
    const int* __restrict__ perm, const int* __restrict__ base,
    const float* __restrict__ partial, const int* __restrict__ counts,
    ushort* __restrict__ centB, float* __restrict__ sumq,
    float* __restrict__ invd, unsigned* __restrict__ bars) {
  __shared__ float cent[DN];
  __shared__ float wacc[4];
  __shared__ unsigned elect;
  __shared__ float sv[256];
  __shared__ float stv[256];
  const int g = blockIdx.x >> 3;
  const int s = blockIdx.x & (SPLIT - 1);
  const int t = threadIdx.x;
  const int w = t >> 6;
  const int lane = t & 63;
  const int start = base[g], end = base[g + 1];
  const int nviews = 2 * (end - start);
  const int cnt = counts[g];
  const float invc = 1.0f / (float)cnt;

  // centroid rebuild: thread t owns dims {2t, 2t+1}
  float c0 = 0.f, c1 = 0.f;
#pragma unroll
  for (int sp = 0; sp < SPLIT; ++sp) {
    float2 v = *(const float2*)&partial[(size_t)sp * (KN * DN) + g * DN + t * 2];
    c0 += v.x; c1 += v.y;
  }
  c0 *= invc; c1 *= invc;
  cent[t * 2] = c0; cent[t * 2 + 1] = c1;
  if (s == 0) {
    *(ushort2*)&centB[g * DN + t * 2] = (ushort2){f2bf(c0), f2bf(c1)};
  }
  __syncthreads();

  float cs[8];
#pragma unroll
  for (int k = 0; k < 8; ++k) cs[k] = cent[lane * 8 + k];

  float q = 0.f;
  const int vs = s * 4 + w;   // virtual split 0..31
  for (int j = vs; j < nviews; j += SPLIT * 4) {
    const int idx = perm[start + (j >> 1)];
    const int row = idx + (j & 1) * BN;
    int4 chunk = *(const int4*)(Xb + (size_t)row * DN + lane * 8);
    const ushort* us = (const ushort*)&chunk;
    float ss = 0.f;
#pragma unroll
    for (int k = 0; k < 8; ++k) {
      float diff = bf2f(us[k]) - cs[k];
      ss += diff * diff;
    }
#pragma unroll
    for (int off = 32; off > 0; off >>= 1) ss += __shfl_down(ss, off, 64);
    if (lane == 0) q += sqrtf(sqrtf(ss));
  }
  if (lane == 0) wacc[w] = q;
  __syncthreads();
  if (t == 0) atomAddF(&sumq[g], wacc[0] + wacc[1] + wacc[2] + wacc[3]);

  // ---- last-block-out election: the final block runs k4 (density) ----
  asm volatile("s_waitcnt vmcnt(0)" ::: "memory");   // all waves drain atomics
  __syncthreads();
  if (t == 0) {
    unsigned a = __hip_atomic_fetch_add(&bars[2], 1u, __ATOMIC_RELAXED,
                                        __HIP_MEMORY_SCOPE_AGENT);
    elect = (a + 1u == (unsigned)(KN * SPLIT)) ? 1u : 0u;
  }
  __syncthreads();
  if (!elect) return;

  // ---- k4 body (block-uniform branch; R4-verified logic) ----
  const int cntt = counts[t];
  const bool valid = cntt > 1;
  const float sq = __hip_atomic_load(&sumq[t], __ATOMIC_RELAXED,
                                     __HIP_MEMORY_SCOPE_AGENT);
  float dens = 0.f;
  if (valid) dens = (sq / (float)cntt) / logf((float)cntt + 10.f);
  sv[t] = valid ? dens : -INFINITY;
  __syncthreads();
  for (int s2 = 128; s2 > 0; s2 >>= 1) {
    if (t < s2) sv[t] = fmaxf(sv[t], sv[t + s2]);
    __syncthreads();
  }
  const float dmax = sv[0];
  __syncthreads();
  const float d0 = valid ? dens : dmax;
  sv[t] = d0;
  __syncthreads();
  int rank = 0;
  for (int j = 0; j < 256; ++j) {
    float vj = sv[j];
    rank += (vj < d0) || (vj == d0 && j < t);
  }
  stv[rank] = d0;
  __syncthreads();
  const float q10 = 0.5f * (stv[25] + stv[26]);
  const float q90 = 0.5f * (stv[229] + stv[230]);
  const float dc = fminf(fmaxf(d0, q10), q90);
  sv[t] = dc;
  __syncthreads();
  for (int s2 = 128; s2 > 0; s2 >>= 1) {
    if (t < s2) sv[t] += sv[t + s2];
    __syncthreads();
  }
  invd[t] = (sv[0] * (1.0f / 256.f)) / (0.1f * dc);
}

// ---- k5: MFMA GEMM (M=64 per block) + fused softmax loss + final mean ----
// M=128->64: acc 128->64 AGPRs; (256,3) => 3 blocks/CU (was 2) for TLP over
// the per-K-step global_load_lds drain. Grid 1024; LDS 41KB fits 3/CU.
#define TAB (64 * 128)    // A tile bytes
#define TBB (256 * 128)   // B tile bytes
__global__ __launch_bounds__(256, 3) void k5_mfma(const ushort* __restrict__ Xb,
    const ushort* __restrict__ centB, const int* __restrict__ subject,
    const int* __restrict__ labels, const float* __restrict__ invd,
    float* __restrict__ losssum, float* __restrict__ out,
    unsigned* __restrict__ bars) {
  __shared__ char smem[TAB + TBB + 1024];
  char* ldsA = smem;                 // [64 rows][128B, swizzled]
  char* ldsB = smem + TAB;           // [256 rows][128B, swizzled]
  float* maxbuf = (float*)smem;      // epilogue aliases ldsA: [4][64]
  float* gmax = (float*)(smem + 2048);    // [64]
  float* ebuf = (float*)(smem + 2560);    // [4][64]
  float* zbuf = (float*)(smem + 4608);    // [4][64]
  int* labs = (int*)(smem + TAB + TBB);
  int* subs = labs + 64;

  const int t = threadIdx.x;
  const int w = t >> 6;
  const int lane = t & 63;
  const int quad = lane >> 4;
  const int n16 = lane & 15;
  const int li = lane >> 3;          // row within an 8-row DMA chunk
  const int lc = lane & 7;           // lds slot chunk
  const int srcc = lc ^ li;          // swizzled source chunk
  const int rowbase = blockIdx.x * 64;

  if (t < 64) {
    int b = (rowbase + t) & (BN - 1);
    labs[t] = labels[b];
    subs[t] = subject[b];
  }

  f32x4 acc[4][4];
#pragma unroll
  for (int mt = 0; mt < 4; ++mt)
#pragma unroll
    for (int nt = 0; nt < 4; ++nt) acc[mt][nt] = (f32x4){0.f, 0.f, 0.f, 0.f};

  const ushort* Arow = Xb + (size_t)rowbase * DN;

  for (int k0 = 0; k0 < DN; k0 += 64) {
    __syncthreads();
#pragma unroll
    for (int q = 0; q < 2; ++q) {
      const int r0 = w * 16 + q * 8;
      async16(Arow + (size_t)(r0 + li) * DN + k0 + srcc * 8, ldsA + r0 * 128);
    }
#pragma unroll
    for (int q = 0; q < 8; ++q) {
      const int g0 = w * 64 + q * 8;
      async16(centB + (size_t)(g0 + li) * DN + k0 + srcc * 8, ldsB + g0 * 128);
    }
    __syncthreads();
#pragma unroll
    for (int s = 0; s < 2; ++s) {
      const int csw = ((s * 4 + quad) ^ (n16 & 7)) * 16;
      bf16x8 bfr[4];
#pragma unroll
      for (int nt = 0; nt < 4; ++nt) {
        int g = w * 64 + nt * 16 + n16;
        bfr[nt] = *(bf16x8*)(ldsB + g * 128 + csw);
      }
#pragma unroll
      for (int mt = 0; mt < 4; ++mt) {
        bf16x8 afr = *(bf16x8*)(ldsA + (mt * 16 + n16) * 128 + csw);
#pragma unroll
        for (int nt = 0; nt < 4; ++nt)
          acc[mt][nt] = __builtin_amdgcn_mfma_f32_16x16x32_bf16(afr, bfr[nt], acc[mt][nt], 0, 0, 0);
      }
    }
  }

  float iv[4];
#pragma unroll
  for (int nt = 0; nt < 4; ++nt) iv[nt] = invd[w * 64 + nt * 16 + n16];

  __syncthreads();

#pragma unroll
  for (int mt = 0; mt < 4; ++mt) {
#pragma unroll
    for (int r = 0; r < 4; ++r) {
      float mm = -INFINITY;
#pragma unroll
      for (int nt = 0; nt < 4; ++nt) mm = fmaxf(mm, acc[mt][nt][r] * iv[nt]);
#pragma unroll
      for (int off = 1; off < 16; off <<= 1) mm = fmaxf(mm, __shfl_xor(mm, off, 64));
      if (n16 == 0) maxbuf[w * 64 + mt * 16 + quad * 4 + r] = mm;
    }
  }
  __syncthreads();
  if (t < 64)
    gmax[t] = fmaxf(fmaxf(maxbuf[t], maxbuf[64 + t]),
                    fmaxf(maxbuf[128 + t], maxbuf[192 + t]));
  __syncthreads();

#pragma unroll
  for (int mt = 0; mt < 4; ++mt) {
#pragma unroll
    for (int r = 0; r < 4; ++r) {
      const int row = mt * 16 + quad * 4 + r;
      const float gm = gmax[row];
      const int lab = labs[row];
      const int sub = subs[row];
      float e = 0.f, z = 0.f;
      if ((n16 & 7) == lab) {
#pragma unroll
        for (int nt = 0; nt < 4; ++nt) {
          int gdiv8 = w * 8 + nt * 2 + (n16 >> 3);
          if (gdiv8 != sub) {
            float svv = acc[mt][nt][r] * iv[nt] - gm;
            e += expf(svv);
            z += svv;
          }
        }
      }
#pragma unroll
      for (int off = 1; off < 16; off <<= 1) {
        e += __shfl_xor(e, off, 64);
        z += __shfl_xor(z, off, 64);
      }
      if (n16 == 0) {
        ebuf[w * 64 + row] = e;
        zbuf[w * 64 + row] = z;
      }
    }
  }
  __syncthreads();

  float lsum = 0.f;
  if (t < 64) {
    float e = ebuf[t] + ebuf[64 + t] + ebuf[128 + t] + ebuf[192 + t];
    float z = zbuf[t] + zbuf[64 + t] + zbuf[128 + t] + zbuf[192 + t];
    lsum = logf(225.f + e) - z * (1.0f / 31.0f);
  }
#pragma unroll
  for (int off = 32; off > 0; off >>= 1) lsum += __shfl_down(lsum, off, 64);
  if (lane == 0 && lsum != 0.f) atomAddF(losssum, lsum);

  // ---- fused k6: last-block-out final mean (verified pattern) ----
  asm volatile("s_waitcnt vmcnt(0)" ::: "memory");
  __syncthreads();
  if (t == 0) {
    unsigned a = __hip_atomic_fetch_add(&bars[4], 1u, __ATOMIC_RELAXED,
                                        __HIP_MEMORY_SCOPE_AGENT);
    if (a + 1u == (unsigned)(N2 / 64)) {
      const float ls = __hip_atomic_load(losssum, __ATOMIC_RELAXED,
                                         __HIP_MEMORY_SCOPE_AGENT);
      out[0] = ls * (1.0f / (float)N2);
    }
  }
}

extern "C" void kernel_launch(void* const* d_in, const int* in_sizes, int n_in,
                              void* d_out, int out_size, void* d_ws, size_t ws_size,
                              hipStream_t stream) {
  const float* X = (const float*)d_in[0];
  const int* subject = (const int*)d_in[1];
  const int* labels = (const int*)d_in[2];
  char* ws = (char*)d_ws;
  ushort* Xb = (ushort*)(ws + OFF_XBF);
  float* partial = (float*)(ws + OFF_PART);
  ushort* centB = (ushort*)(ws + OFF_CENTB);
  int* perm = (int*)(ws + OFF_PERM);
  int* basep = (int*)(ws + OFF_BASE);
  int* offw = (int*)(ws + OFF_OFFW);
  int* counts = (int*)(ws + OFF_COUNTS);
  float* sumq = (float*)(ws + OFF_SUMQ);
  float* invd = (float*)(ws + OFF_INVD);
  float* losssum = (float*)(ws + OFF_LOSS);
  unsigned* bars = (unsigned*)(ws + OFF_BARS);

  hipMemsetAsync(ws + ZERO_OFF, 0, ZERO_BYTES, stream);
  k0_all<<<32, 256, 0, stream>>>(subject, labels, counts, basep, offw, perm, bars);
  k1_sums<<<KN * SPLIT, 256, 0, stream>>>(X, perm, basep, Xb, partial);
  k3_dist<<<KN * SPLIT, 256, 0, stream>>>(Xb, perm, basep, partial, counts,
                                          centB, sumq, invd, bars);
  k5_mfma<<<N2 / 64, 256, 0, stream>>>(Xb, centB, subject, labels, invd,
                                       losssum, (float*)d_out, bars);
}

// Round 6
// 304.077 us; speedup vs baseline: 1.0633x; 1.0633x over previous
//
#include <hip/hip_runtime.h>
#include <math.h>

// Problem constants
#define BN 32768
#define DN 512
#define SN 32
#define LN 8
#define KN 256
#define N2 65536   // 2*BN
#define SPLIT 8    // blocks per group in k1/k3

typedef __attribute__((ext_vector_type(8))) short bf16x8;
typedef __attribute__((ext_vector_type(4))) float f32x4;

// workspace layout (byte offsets) — baseline layout + bars appended
#define OFF_XBF     0ull            // ushort[N2*DN]            67108864
#define OFF_PART    67108864ull     // float[SPLIT*KN*DN]        4194304
#define OFF_SUMS    71303168ull     // float[KN*DN]               524288
#define OFF_CENTB   71827456ull     // ushort[KN*DN]              262144
#define OFF_PERM    72089600ull     // int[BN]                    131072
#define OFF_BASE    72220672ull     // int[KN+1]                    1028
#define OFF_OFFW    72221700ull     // int[KN]  (zero-based cursor) 1024
#define OFF_COUNTS  72222724ull     // int[KN]                      1024
#define OFF_SUMQ    72223748ull     // float[KN]                    1024
#define OFF_INVD    72224772ull     // float[KN]                    1024
#define OFF_LOSS    72225796ull     // float[1]                        4
#define OFF_BARS    72225800ull     // uint[6]                        24
#define ZERO_OFF    OFF_OFFW
#define ZERO_BYTES  (72225824ull - OFF_OFFW)   // 4124

__device__ __forceinline__ float atomAddF(float* p, float v) {
  return unsafeAtomicAdd(p, v);   // hw global_atomic_add_f32 (coherence point)
}

// Relaxed grid barrier (k0 only: 32 blocks). All values crossing it are
// device-scope atomics read back with agent-scope loads -> no fences needed.
__device__ __forceinline__ void gridbar_relaxed(unsigned* cnt, unsigned* flag,
                                                unsigned nblocks) {
  asm volatile("s_waitcnt vmcnt(0)" ::: "memory");
  __syncthreads();
  if (threadIdx.x == 0) {
    unsigned a = __hip_atomic_fetch_add(cnt, 1u, __ATOMIC_RELAXED,
                                        __HIP_MEMORY_SCOPE_AGENT);
    if (a + 1u == nblocks) {
      __hip_atomic_store(flag, 1u, __ATOMIC_RELAXED, __HIP_MEMORY_SCOPE_AGENT);
    } else {
      while (!__hip_atomic_load(flag, __ATOMIC_RELAXED, __HIP_MEMORY_SCOPE_AGENT))
        __builtin_amdgcn_s_sleep(16);
    }
  }
  __syncthreads();
}

__device__ __forceinline__ ushort f2bf(float x) {
  union { float f; unsigned u; } v; v.f = x;
  unsigned u = v.u;
  unsigned r = (u + 0x7fffu + ((u >> 16) & 1u)) >> 16;  // RNE
  return (ushort)r;
}

__device__ __forceinline__ float bf2f(ushort x) {
  union { unsigned u; float f; } v; v.u = ((unsigned)x) << 16;
  return v.f;
}

// async 16B/lane global->LDS DMA (lands at lds base + lane*16)
__device__ __forceinline__ void async16(const void* g, void* l) {
  __builtin_amdgcn_global_load_lds(
      (const __attribute__((address_space(1))) unsigned int*)g,
      (__attribute__((address_space(3))) unsigned int*)l, 16, 0, 0);
}

// ---- k0: fused gid/hist + scan + scatter (32 blocks, relaxed grid-barrier) ----
// R3/R4/R5-verified.
__global__ __launch_bounds__(256) void k0_all(const int* __restrict__ subject,
    const int* __restrict__ labels, int* __restrict__ counts, int* __restrict__ base,
    int* __restrict__ offw, int* __restrict__ perm, unsigned* __restrict__ bars) {
  __shared__ int lhist[KN];
  __shared__ int sh[KN];
  __shared__ int lbase[KN];
  const int t = threadIdx.x;
  const int b0 = blockIdx.x * 1024;
  lhist[t] = 0;
  __syncthreads();
  int g[4], lr[4];
#pragma unroll
  for (int k = 0; k < 4; ++k) {
    const int b = b0 + k * 256 + t;
    g[k] = subject[b] * LN + labels[b];
    lr[k] = atomicAdd(&lhist[g[k]], 1);
  }
  __syncthreads();
  const int h = lhist[t];
  if (h) atomicAdd(&counts[t], 2 * h);
  gridbar_relaxed(&bars[0], &bars[1], 32);
  const int rows = ((int)__hip_atomic_load((unsigned*)&counts[t], __ATOMIC_RELAXED,
                                           __HIP_MEMORY_SCOPE_AGENT)) >> 1;
  sh[t] = rows;
  __syncthreads();
  for (int d = 1; d < 256; d <<= 1) {
    int add = (t >= d) ? sh[t - d] : 0;
    __syncthreads();
    sh[t] += add;
    __syncthreads();
  }
  const int excl = sh[t] - rows;
  if (blockIdx.x == 0) {
    base[t] = excl;
    if (t == 255) base[256] = sh[255];
  }
  if (h) lbase[t] = excl + atomicAdd(&offw[t], h);
  __syncthreads();
#pragma unroll
  for (int k = 0; k < 4; ++k)
    perm[lbase[g[k]] + lr[k]] = b0 + k * 256 + t;
}

// ---- k1: sorted segment-reduce group sums + f32->bf16 conversion ----
// Baseline-proven form. Each wave owns an independent row stream.
__global__ __launch_bounds__(256) void k1_sums(const float* __restrict__ X,
    const int* __restrict__ perm, const int* __restrict__ base,
    ushort* __restrict__ Xb, float* __restrict__ partial) {
  __shared__ float buf[4 * 512];
  const int g = blockIdx.x >> 3;
  const int s = blockIdx.x & (SPLIT - 1);
  const int t = threadIdx.x;
  const int w = t >> 6;
  const int lane = t & 63;
  const int start = base[g], end = base[g + 1];
  const int vs = s * 4 + w;              // stream 0..31

  float4 a0 = {0.f, 0.f, 0.f, 0.f};
  float4 a1 = {0.f, 0.f, 0.f, 0.f};

  int i = start + vs;
  if (i < end) {
    int idx = perm[i];
    const float* bp = X + (size_t)idx * 1024 + lane * 4;
    float4 x0 = *(const float4*)(bp);
    float4 x1 = *(const float4*)(bp + 256);
    float4 x2 = *(const float4*)(bp + 512);
    float4 x3 = *(const float4*)(bp + 768);
    while (true) {
      const int inext = i + 32;
      int idxn = idx;
      float4 y0 = x0, y1 = x1, y2 = x2, y3 = x3;
      if (inext < end) {
        idxn = perm[inext];
        const float* bn = X + (size_t)idxn * 1024 + lane * 4;
        y0 = *(const float4*)(bn);
        y1 = *(const float4*)(bn + 256);
        y2 = *(const float4*)(bn + 512);
        y3 = *(const float4*)(bn + 768);
      }
      a0.x += x0.x + x2.x; a0.y += x0.y + x2.y;
      a0.z += x0.z + x2.z; a0.w += x0.w + x2.w;
      a1.x += x1.x + x3.x; a1.y += x1.y + x3.y;
      a1.z += x1.z + x3.z; a1.w += x1.w + x3.w;
      ushort* xb0 = Xb + (size_t)idx * DN + lane * 4;
      ushort* xb1 = Xb + (size_t)(idx + BN) * DN + lane * 4;
      *(ushort4*)(xb0)       = (ushort4){f2bf(x0.x), f2bf(x0.y), f2bf(x0.z), f2bf(x0.w)};
      *(ushort4*)(xb0 + 256) = (ushort4){f2bf(x1.x), f2bf(x1.y), f2bf(x1.z), f2bf(x1.w)};
      *(ushort4*)(xb1)       = (ushort4){f2bf(x2.x), f2bf(x2.y), f2bf(x2.z), f2bf(x2.w)};
      *(ushort4*)(xb1 + 256) = (ushort4){f2bf(x3.x), f2bf(x3.y), f2bf(x3.z), f2bf(x3.w)};
      if (inext >= end) break;
      i = inext; idx = idxn; x0 = y0; x1 = y1; x2 = y2; x3 = y3;
    }
  }
  *(float4*)&buf[w * 512 + lane * 4] = a0;
  *(float4*)&buf[w * 512 + 256 + lane * 4] = a1;
  __syncthreads();
  if (t < 128) {
    float4 r = {0.f, 0.f, 0.f, 0.f};
#pragma unroll
    for (int ww = 0; ww < 4; ++ww) {
      float4 v = *(float4*)&buf[ww * 512 + t * 4];
      r.x += v.x; r.y += v.y; r.z += v.z; r.w += v.w;
    }
    *(float4*)&partial[((size_t)s * KN + g) * DN + t * 4] = r;
  }
}

// ---- k1b: reduce split partials -> f32 sums + bf16 centroids (baseline) ----
__global__ __launch_bounds__(256) void k1b_cent(const float* __restrict__ partial,
    const int* __restrict__ counts, float* __restrict__ sums,
    ushort* __restrict__ centB) {
  const int i = blockIdx.x * 256 + threadIdx.x;   // over KN*DN, [g][d]
  const int g = i >> 9;
  float ss = 0.f;
#pragma unroll
  for (int s = 0; s < SPLIT; ++s) ss += partial[(size_t)s * (KN * DN) + i];
  sums[i] = ss;
  centB[i] = f2bf(ss / (float)counts[g]);
}

// ---- k3: group-per-block dist^(1/4) accumulation, 1 atomic/block (baseline) ----
__global__ __launch_bounds__(256) void k3_dist(const ushort* __restrict__ Xb,
    const int* __restrict__ perm, const int* __restrict__ base,
    const float* __restrict__ sums, const int* __restrict__ counts,
    float* __restrict__ sumq) {
  __shared__ float wacc[4];
  const int g = blockIdx.x >> 3;
  const int s = blockIdx.x & (SPLIT - 1);
  const int t = threadIdx.x;
  const int w = t >> 6;
  const int lane = t & 63;
  const int start = base[g], end = base[g + 1];
  const int nviews = 2 * (end - start);
  const float invc = 1.0f / (float)counts[g];
  const float* sp = sums + g * DN + lane * 8;
  float4 c0 = *(const float4*)sp;
  float4 c1 = *(const float4*)(sp + 4);
  const float cs[8] = {c0.x * invc, c0.y * invc, c0.z * invc, c0.w * invc,
                       c1.x * invc, c1.y * invc, c1.z * invc, c1.w * invc};
  float q = 0.f;
  const int vs = s * 4 + w;   // virtual split 0..31
  for (int j = vs; j < nviews; j += SPLIT * 4) {
    const int idx = perm[start + (j >> 1)];
    const int row = idx + (j & 1) * BN;
    int4 chunk = *(const int4*)(Xb + (size_t)row * DN + lane * 8);
    const ushort* us = (const ushort*)&chunk;
    float ss = 0.f;
#pragma unroll
    for (int k = 0; k < 8; ++k) {
      float diff = bf2f(us[k]) - cs[k];
      ss += diff * diff;
    }
#pragma unroll
    for (int off = 32; off > 0; off >>= 1) ss += __shfl_down(ss, off, 64);
    if (lane == 0) q += sqrtf(sqrtf(ss));
  }
  if (lane == 0) wacc[w] = q;
  __syncthreads();
  if (t == 0) atomAddF(&sumq[g], wacc[0] + wacc[1] + wacc[2] + wacc[3]);
}

// ---- k4: density -> invd (baseline standalone, 1 block) ----
__global__ __launch_bounds__(256) void k4_density(const float* __restrict__ sumq,
    const int* __restrict__ counts, float* __restrict__ invd) {
  __shared__ float sv[256];
  __shared__ float st[256];
  const int t = threadIdx.x;
  const int cnt = counts[t];
  const bool valid = cnt > 1;
  float dens = 0.f;
  if (valid) dens = (sumq[t] / (float)cnt) / logf((float)cnt + 10.f);
  sv[t] = valid ? dens : -INFINITY;
  __syncthreads();
  for (int s = 128; s > 0; s >>= 1) {
    if (t < s) sv[t] = fmaxf(sv[t], sv[t + s]);
    __syncthreads();
  }
  const float dmax = sv[0];
  __syncthreads();
  const float d0 = valid ? dens : dmax;
  sv[t] = d0;
  __syncthreads();
  int rank = 0;
  for (int j = 0; j < 256; ++j) {
    float vj = sv[j];
    rank += (vj < d0) || (vj == d0 && j < t);
  }
  st[rank] = d0;
  __syncthreads();
  const float q10 = 0.5f * (st[25] + st[26]);
  const float q90 = 0.5f * (st[229] + st[230]);
  const float dc = fminf(fmaxf(d0, q10), q90);
  sv[t] = dc;
  __syncthreads();
  for (int s = 128; s > 0; s >>= 1) {
    if (t < s) sv[t] += sv[t + s];
    __syncthreads();
  }
  const float mean = sv[0] * (1.0f / 256.f);
  invd[t] = mean / (0.1f * dc);
}

// ---- k5: MFMA GEMM, A double-buffered LDS + B DIRECT FROM L2 + fused loss ----
// B (centB, 256KB) is L2/L3-resident: the XOR-swizzle algebra cancels so the
// register fragment is just centB[g*DN + k0 + (s*4+quad)*8]. Removes 8 of 12
// DMAs per K-step. A is double-buffered: stage tile k+1 before computing k,
// one barrier per step -> DMA lands under the MFMA phase instead of stalling.
// NOTE: (256,2) required — 128 acc VGPRs; watch WRITE_SIZE for spill signature.
#define TAB (128 * 128)   // one A buffer: 16 KB
__global__ __launch_bounds__(256, 2) void k5_mfma(const ushort* __restrict__ Xb,
    const ushort* __restrict__ centB, const int* __restrict__ subject,
    const int* __restrict__ labels, const float* __restrict__ invd,
    float* __restrict__ losssum, float* __restrict__ out,
    unsigned* __restrict__ bars) {
  __shared__ char smem[2 * TAB + 1024];
  float* maxbuf = (float*)smem;           // epilogue aliases ldsA: [4][128]
  float* gmax = (float*)(smem + 2048);    // [128]
  float* ebuf = (float*)(smem + 2560);    // [4][128]
  float* zbuf = (float*)(smem + 4608);    // [4][128]
  int* labs = (int*)(smem + 2 * TAB);
  int* subs = labs + 128;

  const int t = threadIdx.x;
  const int w = t >> 6;
  const int lane = t & 63;
  const int quad = lane >> 4;
  const int n16 = lane & 15;
  const int li = lane >> 3;          // row within an 8-row DMA chunk
  const int lc = lane & 7;           // lds slot chunk
  const int srcc = lc ^ li;          // swizzled source chunk
  const int rowbase = blockIdx.x * 128;

  if (t < 128) {
    int b = (rowbase + t) & (BN - 1);
    labs[t] = labels[b];
    subs[t] = subject[b];
  }

  f32x4 acc[8][4];
#pragma unroll
  for (int mt = 0; mt < 8; ++mt)
#pragma unroll
    for (int nt = 0; nt < 4; ++nt) acc[mt][nt] = (f32x4){0.f, 0.f, 0.f, 0.f};

  const ushort* Arow = Xb + (size_t)rowbase * DN;

  // prologue: stage k0=0 into buffer 0
#pragma unroll
  for (int q = 0; q < 4; ++q) {
    const int r0 = w * 32 + q * 8;
    async16(Arow + (size_t)(r0 + li) * DN + srcc * 8, smem + r0 * 128);
  }
  __syncthreads();   // compiler drains vmcnt before s_barrier

  int ab = 0;        // current A buffer byte offset (0 or TAB)
  for (int k0 = 0; k0 < DN; k0 += 64) {
    if (k0 + 64 < DN) {
#pragma unroll
      for (int q = 0; q < 4; ++q) {
        const int r0 = w * 32 + q * 8;
        async16(Arow + (size_t)(r0 + li) * DN + (k0 + 64) + srcc * 8,
                smem + (ab ^ TAB) + r0 * 128);
      }
    }
#pragma unroll
    for (int s = 0; s < 2; ++s) {
      const int chunk = s * 4 + quad;
      const int csw = (chunk ^ (n16 & 7)) * 16;
      bf16x8 bfr[4];
#pragma unroll
      for (int nt = 0; nt < 4; ++nt) {
        const int g = w * 64 + nt * 16 + n16;
        bfr[nt] = *(const bf16x8*)(centB + (size_t)g * DN + k0 + chunk * 8);
      }
#pragma unroll
      for (int mt = 0; mt < 8; ++mt) {
        bf16x8 afr = *(bf16x8*)(smem + ab + (mt * 16 + n16) * 128 + csw);
#pragma unroll
        for (int nt = 0; nt < 4; ++nt)
          acc[mt][nt] = __builtin_amdgcn_mfma_f32_16x16x32_bf16(afr, bfr[nt], acc[mt][nt], 0, 0, 0);
      }
    }
    __syncthreads();   // drains the k0+64 DMAs (landed under this step's MFMA)
    ab ^= TAB;
  }

  float iv[4];
#pragma unroll
  for (int nt = 0; nt < 4; ++nt) iv[nt] = invd[w * 64 + nt * 16 + n16];

#pragma unroll
  for (int mt = 0; mt < 8; ++mt) {
#pragma unroll
    for (int r = 0; r < 4; ++r) {
      float mm = -INFINITY;
#pragma unroll
      for (int nt = 0; nt < 4; ++nt) mm = fmaxf(mm, acc[mt][nt][r] * iv[nt]);
#pragma unroll
      for (int off = 1; off < 16; off <<= 1) mm = fmaxf(mm, __shfl_xor(mm, off, 64));
      if (n16 == 0) maxbuf[w * 128 + mt * 16 + quad * 4 + r] = mm;
    }
  }
  __syncthreads();
  if (t < 128)
    gmax[t] = fmaxf(fmaxf(maxbuf[t], maxbuf[128 + t]),
                    fmaxf(maxbuf[256 + t], maxbuf[384 + t]));
  __syncthreads();

#pragma unroll
  for (int mt = 0; mt < 8; ++mt) {
#pragma unroll
    for (int r = 0; r < 4; ++r) {
      const int row = mt * 16 + quad * 4 + r;
      const float gm = gmax[row];
      const int lab = labs[row];
      const int sub = subs[row];
      float e = 0.f, z = 0.f;
      if ((n16 & 7) == lab) {
#pragma unroll
        for (int nt = 0; nt < 4; ++nt) {
          int gdiv8 = w * 8 + nt * 2 + (n16 >> 3);
          if (gdiv8 != sub) {
            float svv = acc[mt][nt][r] * iv[nt] - gm;
            e += expf(svv);
            z += svv;
          }
        }
      }
#pragma unroll
      for (int off = 1; off < 16; off <<= 1) {
        e += __shfl_xor(e, off, 64);
        z += __shfl_xor(z, off, 64);
      }
      if (n16 == 0) {
        ebuf[w * 128 + row] = e;
        zbuf[w * 128 + row] = z;
      }
    }
  }
  __syncthreads();

  float lsum = 0.f;
  if (t < 128) {
    float e = ebuf[t] + ebuf[128 + t] + ebuf[256 + t] + ebuf[384 + t];
    float z = zbuf[t] + zbuf[128 + t] + zbuf[256 + t] + zbuf[384 + t];
    lsum = logf(225.f + e) - z * (1.0f / 31.0f);
  }
#pragma unroll
  for (int off = 32; off > 0; off >>= 1) lsum += __shfl_down(lsum, off, 64);
  if (lane == 0 && lsum != 0.f) atomAddF(losssum, lsum);

  // ---- fused k6: last-block-out final mean (verified pattern) ----
  asm volatile("s_waitcnt vmcnt(0)" ::: "memory");
  __syncthreads();
  if (t == 0) {
    unsigned a = __hip_atomic_fetch_add(&bars[4], 1u, __ATOMIC_RELAXED,
                                        __HIP_MEMORY_SCOPE_AGENT);
    if (a + 1u == (unsigned)(N2 / 128)) {
      const float ls = __hip_atomic_load(losssum, __ATOMIC_RELAXED,
                                         __HIP_MEMORY_SCOPE_AGENT);
      out[0] = ls * (1.0f / (float)N2);
    }
  }
}

extern "C" void kernel_launch(void* const* d_in, const int* in_sizes, int n_in,
                              void* d_out, int out_size, void* d_ws, size_t ws_size,
                              hipStream_t stream) {
  const float* X = (const float*)d_in[0];
  const int* subject = (const int*)d_in[1];
  const int* labels = (const int*)d_in[2];
  char* ws = (char*)d_ws;
  ushort* Xb = (ushort*)(ws + OFF_XBF);
  float* partial = (float*)(ws + OFF_PART);
  float* sums = (float*)(ws + OFF_SUMS);
  ushort* centB = (ushort*)(ws + OFF_CENTB);
  int* perm = (int*)(ws + OFF_PERM);
  int* basep = (int*)(ws + OFF_BASE);
  int* offw = (int*)(ws + OFF_OFFW);
  int* counts = (int*)(ws + OFF_COUNTS);
  float* sumq = (float*)(ws + OFF_SUMQ);
  float* invd = (float*)(ws + OFF_INVD);
  float* losssum = (float*)(ws + OFF_LOSS);
  unsigned* bars = (unsigned*)(ws + OFF_BARS);

  hipMemsetAsync(ws + ZERO_OFF, 0, ZERO_BYTES, stream);
  k0_all<<<32, 256, 0, stream>>>(subject, labels, counts, basep, offw, perm, bars);
  k1_sums<<<KN * SPLIT, 256, 0, stream>>>(X, perm, basep, Xb, partial);
  k1b_cent<<<(KN * DN) / 256, 256, 0, stream>>>(partial, counts, sums, centB);
  k3_dist<<<KN * SPLIT, 256, 0, stream>>>(Xb, perm, basep, sums, counts, sumq);
  k4_density<<<1, 256, 0, stream>>>(sumq, counts, invd);
  k5_mfma<<<N2 / 128, 256, 0, stream>>>(Xb, centB, subject, labels, invd,
                                        losssum, (float*)d_out, bars);
}

// Round 7
// 303.589 us; speedup vs baseline: 1.0650x; 1.0016x over previous
//
#include <hip/hip_runtime.h>
#include <math.h>

// Problem constants
#define BN 32768
#define DN 512
#define SN 32
#define LN 8
#define KN 256
#define N2 65536   // 2*BN
#define SPLIT 8    // blocks per group in k1/k3

typedef __attribute__((ext_vector_type(8))) short bf16x8;
typedef __attribute__((ext_vector_type(4))) float f32x4;

// workspace layout (byte offsets) — baseline layout + bars appended
#define OFF_XBF     0ull            // ushort[N2*DN]            67108864
#define OFF_PART    67108864ull     // float[SPLIT*KN*DN]        4194304
#define OFF_SUMS    71303168ull     // float[KN*DN]               524288
#define OFF_CENTB   71827456ull     // ushort[KN*DN]              262144
#define OFF_PERM    72089600ull     // int[BN]                    131072
#define OFF_BASE    72220672ull     // int[KN+1]                    1028
#define OFF_OFFW    72221700ull     // int[KN]  (zero-based cursor) 1024
#define OFF_COUNTS  72222724ull     // int[KN]                      1024
#define OFF_SUMQ    72223748ull     // float[KN]                    1024
#define OFF_INVD    72224772ull     // float[KN]                    1024
#define OFF_LOSS    72225796ull     // float[1]                        4
#define OFF_BARS    72225800ull     // uint[6]                        24
#define ZERO_OFF    OFF_OFFW
#define ZERO_BYTES  (72225824ull - OFF_OFFW)   // 4124

__device__ __forceinline__ float atomAddF(float* p, float v) {
  return unsafeAtomicAdd(p, v);   // hw global_atomic_add_f32 (coherence point)
}

// Relaxed grid barrier (k0 only: 32 blocks). All values crossing it are
// device-scope atomics read back with agent-scope loads -> no fences needed.
__device__ __forceinline__ void gridbar_relaxed(unsigned* cnt, unsigned* flag,
                                                unsigned nblocks) {
  asm volatile("s_waitcnt vmcnt(0)" ::: "memory");
  __syncthreads();
  if (threadIdx.x == 0) {
    unsigned a = __hip_atomic_fetch_add(cnt, 1u, __ATOMIC_RELAXED,
                                        __HIP_MEMORY_SCOPE_AGENT);
    if (a + 1u == nblocks) {
      __hip_atomic_store(flag, 1u, __ATOMIC_RELAXED, __HIP_MEMORY_SCOPE_AGENT);
    } else {
      while (!__hip_atomic_load(flag, __ATOMIC_RELAXED, __HIP_MEMORY_SCOPE_AGENT))
        __builtin_amdgcn_s_sleep(16);
    }
  }
  __syncthreads();
}

__device__ __forceinline__ ushort f2bf(float x) {
  union { float f; unsigned u; } v; v.f = x;
  unsigned u = v.u;
  unsigned r = (u + 0x7fffu + ((u >> 16) & 1u)) >> 16;  // RNE
  return (ushort)r;
}

__device__ __forceinline__ float bf2f(ushort x) {
  union { unsigned u; float f; } v; v.u = ((unsigned)x) << 16;
  return v.f;
}

// async 16B/lane global->LDS DMA (lands at lds base + lane*16)
__device__ __forceinline__ void async16(const void* g, void* l) {
  __builtin_amdgcn_global_load_lds(
      (const __attribute__((address_space(1))) unsigned int*)g,
      (__attribute__((address_space(3))) unsigned int*)l, 16, 0, 0);
}

// ---- k0: fused gid/hist + scan + scatter (32 blocks, relaxed grid-barrier) ----
// R3-R6-verified.
__global__ __launch_bounds__(256) void k0_all(const int* __restrict__ subject,
    const int* __restrict__ labels, int* __restrict__ counts, int* __restrict__ base,
    int* __restrict__ offw, int* __restrict__ perm, unsigned* __restrict__ bars) {
  __shared__ int lhist[KN];
  __shared__ int sh[KN];
  __shared__ int lbase[KN];
  const int t = threadIdx.x;
  const int b0 = blockIdx.x * 1024;
  lhist[t] = 0;
  __syncthreads();
  int g[4], lr[4];
#pragma unroll
  for (int k = 0; k < 4; ++k) {
    const int b = b0 + k * 256 + t;
    g[k] = subject[b] * LN + labels[b];
    lr[k] = atomicAdd(&lhist[g[k]], 1);
  }
  __syncthreads();
  const int h = lhist[t];
  if (h) atomicAdd(&counts[t], 2 * h);
  gridbar_relaxed(&bars[0], &bars[1], 32);
  const int rows = ((int)__hip_atomic_load((unsigned*)&counts[t], __ATOMIC_RELAXED,
                                           __HIP_MEMORY_SCOPE_AGENT)) >> 1;
  sh[t] = rows;
  __syncthreads();
  for (int d = 1; d < 256; d <<= 1) {
    int add = (t >= d) ? sh[t - d] : 0;
    __syncthreads();
    sh[t] += add;
    __syncthreads();
  }
  const int excl = sh[t] - rows;
  if (blockIdx.x == 0) {
    base[t] = excl;
    if (t == 255) base[256] = sh[255];
  }
  if (h) lbase[t] = excl + atomicAdd(&offw[t], h);
  __syncthreads();
#pragma unroll
  for (int k = 0; k < 4; ++k)
    perm[lbase[g[k]] + lr[k]] = b0 + k * 256 + t;
}

// ---- k1: sorted segment-reduce group sums + f32->bf16 conversion ----
// Baseline-proven form. Each wave owns an independent row stream.
__global__ __launch_bounds__(256) void k1_sums(const float* __restrict__ X,
    const int* __restrict__ perm, const int* __restrict__ base,
    ushort* __restrict__ Xb, float* __restrict__ partial) {
  __shared__ float buf[4 * 512];
  const int g = blockIdx.x >> 3;
  const int s = blockIdx.x & (SPLIT - 1);
  const int t = threadIdx.x;
  const int w = t >> 6;
  const int lane = t & 63;
  const int start = base[g], end = base[g + 1];
  const int vs = s * 4 + w;              // stream 0..31

  float4 a0 = {0.f, 0.f, 0.f, 0.f};
  float4 a1 = {0.f, 0.f, 0.f, 0.f};

  int i = start + vs;
  if (i < end) {
    int idx = perm[i];
    const float* bp = X + (size_t)idx * 1024 + lane * 4;
    float4 x0 = *(const float4*)(bp);
    float4 x1 = *(const float4*)(bp + 256);
    float4 x2 = *(const float4*)(bp + 512);
    float4 x3 = *(const float4*)(bp + 768);
    while (true) {
      const int inext = i + 32;
      int idxn = idx;
      float4 y0 = x0, y1 = x1, y2 = x2, y3 = x3;
      if (inext < end) {
        idxn = perm[inext];
        const float* bn = X + (size_t)idxn * 1024 + lane * 4;
        y0 = *(const float4*)(bn);
        y1 = *(const float4*)(bn + 256);
        y2 = *(const float4*)(bn + 512);
        y3 = *(const float4*)(bn + 768);
      }
      a0.x += x0.x + x2.x; a0.y += x0.y + x2.y;
      a0.z += x0.z + x2.z; a0.w += x0.w + x2.w;
      a1.x += x1.x + x3.x; a1.y += x1.y + x3.y;
      a1.z += x1.z + x3.z; a1.w += x1.w + x3.w;
      ushort* xb0 = Xb + (size_t)idx * DN + lane * 4;
      ushort* xb1 = Xb + (size_t)(idx + BN) * DN + lane * 4;
      *(ushort4*)(xb0)       = (ushort4){f2bf(x0.x), f2bf(x0.y), f2bf(x0.z), f2bf(x0.w)};
      *(ushort4*)(xb0 + 256) = (ushort4){f2bf(x1.x), f2bf(x1.y), f2bf(x1.z), f2bf(x1.w)};
      *(ushort4*)(xb1)       = (ushort4){f2bf(x2.x), f2bf(x2.y), f2bf(x2.z), f2bf(x2.w)};
      *(ushort4*)(xb1 + 256) = (ushort4){f2bf(x3.x), f2bf(x3.y), f2bf(x3.z), f2bf(x3.w)};
      if (inext >= end) break;
      i = inext; idx = idxn; x0 = y0; x1 = y1; x2 = y2; x3 = y3;
    }
  }
  *(float4*)&buf[w * 512 + lane * 4] = a0;
  *(float4*)&buf[w * 512 + 256 + lane * 4] = a1;
  __syncthreads();
  if (t < 128) {
    float4 r = {0.f, 0.f, 0.f, 0.f};
#pragma unroll
    for (int ww = 0; ww < 4; ++ww) {
      float4 v = *(float4*)&buf[ww * 512 + t * 4];
      r.x += v.x; r.y += v.y; r.z += v.z; r.w += v.w;
    }
    *(float4*)&partial[((size_t)s * KN + g) * DN + t * 4] = r;
  }
}

// ---- k1b: reduce split partials -> f32 sums + bf16 centroids (baseline) ----
__global__ __launch_bounds__(256) void k1b_cent(const float* __restrict__ partial,
    const int* __restrict__ counts, float* __restrict__ sums,
    ushort* __restrict__ centB) {
  const int i = blockIdx.x * 256 + threadIdx.x;   // over KN*DN, [g][d]
  const int g = i >> 9;
  float ss = 0.f;
#pragma unroll
  for (int s = 0; s < SPLIT; ++s) ss += partial[(size_t)s * (KN * DN) + i];
  sums[i] = ss;
  centB[i] = f2bf(ss / (float)counts[g]);
}

// ---- k3: group-per-block dist^(1/4) accumulation, 1 atomic/block (baseline) ----
__global__ __launch_bounds__(256) void k3_dist(const ushort* __restrict__ Xb,
    const int* __restrict__ perm, const int* __restrict__ base,
    const float* __restrict__ sums, const int* __restrict__ counts,
    float* __restrict__ sumq) {
  __shared__ float wacc[4];
  const int g = blockIdx.x >> 3;
  const int s = blockIdx.x & (SPLIT - 1);
  const int t = threadIdx.x;
  const int w = t >> 6;
  const int lane = t & 63;
  const int start = base[g], end = base[g + 1];
  const int nviews = 2 * (end - start);
  const float invc = 1.0f / (float)counts[g];
  const float* sp = sums + g * DN + lane * 8;
  float4 c0 = *(const float4*)sp;
  float4 c1 = *(const float4*)(sp + 4);
  const float cs[8] = {c0.x * invc, c0.y * invc, c0.z * invc, c0.w * invc,
                       c1.x * invc, c1.y * invc, c1.z * invc, c1.w * invc};
  float q = 0.f;
  const int vs = s * 4 + w;   // virtual split 0..31
  for (int j = vs; j < nviews; j += SPLIT * 4) {
    const int idx = perm[start + (j >> 1)];
    const int row = idx + (j & 1) * BN;
    int4 chunk = *(const int4*)(Xb + (size_t)row * DN + lane * 8);
    const ushort* us = (const ushort*)&chunk;
    float ss = 0.f;
#pragma unroll
    for (int k = 0; k < 8; ++k) {
      float diff = bf2f(us[k]) - cs[k];
      ss += diff * diff;
    }
#pragma unroll
    for (int off = 32; off > 0; off >>= 1) ss += __shfl_down(ss, off, 64);
    if (lane == 0) q += sqrtf(sqrtf(ss));
  }
  if (lane == 0) wacc[w] = q;
  __syncthreads();
  if (t == 0) atomAddF(&sumq[g], wacc[0] + wacc[1] + wacc[2] + wacc[3]);
}

// ---- k4: density -> invd (baseline standalone, 1 block) ----
__global__ __launch_bounds__(256) void k4_density(const float* __restrict__ sumq,
    const int* __restrict__ counts, float* __restrict__ invd) {
  __shared__ float sv[256];
  __shared__ float st[256];
  const int t = threadIdx.x;
  const int cnt = counts[t];
  const bool valid = cnt > 1;
  float dens = 0.f;
  if (valid) dens = (sumq[t] / (float)cnt) / logf((float)cnt + 10.f);
  sv[t] = valid ? dens : -INFINITY;
  __syncthreads();
  for (int s = 128; s > 0; s >>= 1) {
    if (t < s) sv[t] = fmaxf(sv[t], sv[t + s]);
    __syncthreads();
  }
  const float dmax = sv[0];
  __syncthreads();
  const float d0 = valid ? dens : dmax;
  sv[t] = d0;
  __syncthreads();
  int rank = 0;
  for (int j = 0; j < 256; ++j) {
    float vj = sv[j];
    rank += (vj < d0) || (vj == d0 && j < t);
  }
  st[rank] = d0;
  __syncthreads();
  const float q10 = 0.5f * (st[25] + st[26]);
  const float q90 = 0.5f * (st[229] + st[230]);
  const float dc = fminf(fmaxf(d0, q10), q90);
  sv[t] = dc;
  __syncthreads();
  for (int s = 128; s > 0; s >>= 1) {
    if (t < s) sv[t] += sv[t + s];
    __syncthreads();
  }
  const float mean = sv[0] * (1.0f / 256.f);
  invd[t] = mean / (0.1f * dc);
}

// ---- k5: MFMA GEMM, A double-buffered LDS + B REGISTER-PREFETCHED one
//          K-step ahead from L2 + fused loss + k6 election ----
// R6's B-direct loaded fragments immediately before use (exposed ~200cy L2
// latency x 8 loads/step @ 2 blocks/CU). Fix: load step t+1's B-fragments
// where the A-DMA for t+1 is issued -> a full 64-MFMA phase covers them.
// Same addresses/order as R6 (absmax 0.0 verified). One barrier per K-step.
// VGPR: 128 acc + 32 bcur + 32 bnxt + misc ~ 230 < 256 @ (256,2).
#define TAB (128 * 128)   // one A buffer: 16 KB
__global__ __launch_bounds__(256, 2) void k5_mfma(const ushort* __restrict__ Xb,
    const ushort* __restrict__ centB, const int* __restrict__ subject,
    const int* __restrict__ labels, const float* __restrict__ invd,
    float* __restrict__ losssum, float* __restrict__ out,
    unsigned* __restrict__ bars) {
  __shared__ char smem[2 * TAB + 1024];
  float* maxbuf = (float*)smem;           // epilogue aliases ldsA: [4][128]
  float* gmax = (float*)(smem + 2048);    // [128]
  float* ebuf = (float*)(smem + 2560);    // [4][128]
  float* zbuf = (float*)(smem + 4608);    // [4][128]
  int* labs = (int*)(smem + 2 * TAB);
  int* subs = labs + 128;

  const int t = threadIdx.x;
  const int w = t >> 6;
  const int lane = t & 63;
  const int quad = lane >> 4;
  const int n16 = lane & 15;
  const int li = lane >> 3;          // row within an 8-row DMA chunk
  const int lc = lane & 7;           // lds slot chunk
  const int srcc = lc ^ li;          // swizzled source chunk
  const int rowbase = blockIdx.x * 128;

  if (t < 128) {
    int b = (rowbase + t) & (BN - 1);
    labs[t] = labels[b];
    subs[t] = subject[b];
  }

  f32x4 acc[8][4];
#pragma unroll
  for (int mt = 0; mt < 8; ++mt)
#pragma unroll
    for (int nt = 0; nt < 4; ++nt) acc[mt][nt] = (f32x4){0.f, 0.f, 0.f, 0.f};

  const ushort* Arow = Xb + (size_t)rowbase * DN;
  const ushort* Brow = centB + (size_t)(w * 64 + n16) * DN + quad * 8;
  // fragment (s,nt) of step k0: Brow + nt*16*DN + k0 + s*32  (chunk = s*4+quad)

  // prologue: stage A[0] into buffer 0; load B-regs for step 0
#pragma unroll
  for (int q = 0; q < 4; ++q) {
    const int r0 = w * 32 + q * 8;
    async16(Arow + (size_t)(r0 + li) * DN + srcc * 8, smem + r0 * 128);
  }
  bf16x8 bcur[8];
#pragma unroll
  for (int s = 0; s < 2; ++s)
#pragma unroll
    for (int nt = 0; nt < 4; ++nt)
      bcur[s * 4 + nt] = *(const bf16x8*)(Brow + (size_t)nt * 16 * DN + s * 32);
  __syncthreads();   // drains A[0] DMAs

  int ab = 0;        // current A buffer byte offset (0 or TAB)
#pragma unroll
  for (int k0 = 0; k0 < DN; k0 += 64) {
    bf16x8 bnxt[8];
    if (k0 + 64 < DN) {
      // issue next-step loads FIRST: B-regs + A-DMA land under this step's MFMA
#pragma unroll
      for (int s = 0; s < 2; ++s)
#pragma unroll
        for (int nt = 0; nt < 4; ++nt)
          bnxt[s * 4 + nt] =
              *(const bf16x8*)(Brow + (size_t)nt * 16 * DN + (k0 + 64) + s * 32);
#pragma unroll
      for (int q = 0; q < 4; ++q) {
        const int r0 = w * 32 + q * 8;
        async16(Arow + (size_t)(r0 + li) * DN + (k0 + 64) + srcc * 8,
                smem + (ab ^ TAB) + r0 * 128);
      }
    }
#pragma unroll
    for (int s = 0; s < 2; ++s) {
      const int csw = ((s * 4 + quad) ^ (n16 & 7)) * 16;
#pragma unroll
      for (int mt = 0; mt < 8; ++mt) {
        bf16x8 afr = *(bf16x8*)(smem + ab + (mt * 16 + n16) * 128 + csw);
#pragma unroll
        for (int nt = 0; nt < 4; ++nt)
          acc[mt][nt] = __builtin_amdgcn_mfma_f32_16x16x32_bf16(afr, bcur[s * 4 + nt], acc[mt][nt], 0, 0, 0);
      }
    }
    __syncthreads();   // drains the k0+64 A-DMAs (landed under this step's MFMA)
    ab ^= TAB;
    if (k0 + 64 < DN) {
#pragma unroll
      for (int j = 0; j < 8; ++j) bcur[j] = bnxt[j];
    }
  }

  float iv[4];
#pragma unroll
  for (int nt = 0; nt < 4; ++nt) iv[nt] = invd[w * 64 + nt * 16 + n16];

#pragma unroll
  for (int mt = 0; mt < 8; ++mt) {
#pragma unroll
    for (int r = 0; r < 4; ++r) {
      float mm = -INFINITY;
#pragma unroll
      for (int nt = 0; nt < 4; ++nt) mm = fmaxf(mm, acc[mt][nt][r] * iv[nt]);
#pragma unroll
      for (int off = 1; off < 16; off <<= 1) mm = fmaxf(mm, __shfl_xor(mm, off, 64));
      if (n16 == 0) maxbuf[w * 128 + mt * 16 + quad * 4 + r] = mm;
    }
  }
  __syncthreads();
  if (t < 128)
    gmax[t] = fmaxf(fmaxf(maxbuf[t], maxbuf[128 + t]),
                    fmaxf(maxbuf[256 + t], maxbuf[384 + t]));
  __syncthreads();

#pragma unroll
  for (int mt = 0; mt < 8; ++mt) {
#pragma unroll
    for (int r = 0; r < 4; ++r) {
      const int row = mt * 16 + quad * 4 + r;
      const float gm = gmax[row];
      const int lab = labs[row];
      const int sub = subs[row];
      float e = 0.f, z = 0.f;
      if ((n16 & 7) == lab) {
#pragma unroll
        for (int nt = 0; nt < 4; ++nt) {
          int gdiv8 = w * 8 + nt * 2 + (n16 >> 3);
          if (gdiv8 != sub) {
            float svv = acc[mt][nt][r] * iv[nt] - gm;
            e += expf(svv);
            z += svv;
          }
        }
      }
#pragma unroll
      for (int off = 1; off < 16; off <<= 1) {
        e += __shfl_xor(e, off, 64);
        z += __shfl_xor(z, off, 64);
      }
      if (n16 == 0) {
        ebuf[w * 128 + row] = e;
        zbuf[w * 128 + row] = z;
      }
    }
  }
  __syncthreads();

  float lsum = 0.f;
  if (t < 128) {
    float e = ebuf[t] + ebuf[128 + t] + ebuf[256 + t] + ebuf[384 + t];
    float z = zbuf[t] + zbuf[128 + t] + zbuf[256 + t] + zbuf[384 + t];
    lsum = logf(225.f + e) - z * (1.0f / 31.0f);
  }
#pragma unroll
  for (int off = 32; off > 0; off >>= 1) lsum += __shfl_down(lsum, off, 64);
  if (lane == 0 && lsum != 0.f) atomAddF(losssum, lsum);

  // ---- fused k6: last-block-out final mean (verified pattern) ----
  asm volatile("s_waitcnt vmcnt(0)" ::: "memory");
  __syncthreads();
  if (t == 0) {
    unsigned a = __hip_atomic_fetch_add(&bars[4], 1u, __ATOMIC_RELAXED,
                                        __HIP_MEMORY_SCOPE_AGENT);
    if (a + 1u == (unsigned)(N2 / 128)) {
      const float ls = __hip_atomic_load(losssum, __ATOMIC_RELAXED,
                                         __HIP_MEMORY_SCOPE_AGENT);
      out[0] = ls * (1.0f / (float)N2);
    }
  }
}

extern "C" void kernel_launch(void* const* d_in, const int* in_sizes, int n_in,
                              void* d_out, int out_size, void* d_ws, size_t ws_size,
                              hipStream_t stream) {
  const float* X = (const float*)d_in[0];
  const int* subject = (const int*)d_in[1];
  const int* labels = (const int*)d_in[2];
  char* ws = (char*)d_ws;
  ushort* Xb = (ushort*)(ws + OFF_XBF);
  float* partial = (float*)(ws + OFF_PART);
  float* sums = (float*)(ws + OFF_SUMS);
  ushort* centB = (ushort*)(ws + OFF_CENTB);
  int* perm = (int*)(ws + OFF_PERM);
  int* basep = (int*)(ws + OFF_BASE);
  int* offw = (int*)(ws + OFF_OFFW);
  int* counts = (int*)(ws + OFF_COUNTS);
  float* sumq = (float*)(ws + OFF_SUMQ);
  float* invd = (float*)(ws + OFF_INVD);
  float* losssum = (float*)(ws + OFF_LOSS);
  unsigned* bars = (unsigned*)(ws + OFF_BARS);

  hipMemsetAsync(ws + ZERO_OFF, 0, ZERO_BYTES, stream);
  k0_all<<<32, 256, 0, stream>>>(subject, labels, counts, basep, offw, perm, bars);
  k1_sums<<<KN * SPLIT, 256, 0, stream>>>(X, perm, basep, Xb, partial);
  k1b_cent<<<(KN * DN) / 256, 256, 0, stream>>>(partial, counts, sums, centB);
  k3_dist<<<KN * SPLIT, 256, 0, stream>>>(Xb, perm, basep, sums, counts, sumq);
  k4_density<<<1, 256, 0, stream>>>(sumq, counts, invd);
  k5_mfma<<<N2 / 128, 256, 0, stream>>>(Xb, centB, subject, labels, invd,
                                        losssum, (float*)d_out, bars);
}